// Round 18
// baseline (717.917 us; speedup 1.0000x reference)
//
#include <hip/hip_runtime.h>
#include <hip/hip_bf16.h>
#include <math.h>

// Problem constants (Qwen3 MoE block)
#define T_TOK 2048
#define H_DIM 2048
#define NEXP  64
#define TOPK  8
#define I_DIM 768
#define CAPE  512
#define MTMAX 4   // CAPE/128
#define LDW   40  // LDS row stride in shorts (80B). MUST be multiple of 8 shorts
                  // (16B) or ds_read_b128/ds_write_b64 lose alignment.

typedef short bf16x8 __attribute__((ext_vector_type(8)));
typedef float f32x4  __attribute__((ext_vector_type(4)));

__device__ __forceinline__ unsigned short f2bf(float f) {
  unsigned u = __float_as_uint(f);
  u += 0x7fffu + ((u >> 16) & 1u);   // RNE
  return (unsigned short)(u >> 16);
}
__device__ __forceinline__ float bf2f(unsigned short b) {
  return __uint_as_float(((unsigned)b) << 16);
}
__device__ __forceinline__ unsigned pack2(float lo, float hi) {
  __hip_bfloat162 h = __float22bfloat162_rn(make_float2(lo, hi));  // v_cvt_pk_bf16_f32
  unsigned r; __builtin_memcpy(&r, &h, 4); return r;
}

// ---------------- K1: router (fused x->bf16 conversion + logits + top8) ----
// grid = 128 blocks x 16 tokens. Phase 1: block converts its 16 x-rows to xb
// (replaces the separate k_xcvt kernel; lines stay L2-warm for phase 2).
// Phase 2: 4 tokens per wave, lane = expert id, softmax-top8 + renorm.
__global__ __launch_bounds__(256) void k_router(const float* __restrict__ x,
                                                const float* __restrict__ wr,
                                                unsigned short* __restrict__ xb,
                                                int* __restrict__ topk_idx,
                                                float* __restrict__ topk_w) {
  const int lane = threadIdx.x & 63;
  const int tb = blockIdx.x * 16;            // first token of this block
  // phase 1: convert 16 rows x 2048 = 32768 floats; 256 thr x 8 x 16 iters
  {
    const size_t base = (size_t)tb * H_DIM;
#pragma unroll
    for (int it = 0; it < 16; ++it) {
      const size_t i = base + (size_t)(it * 256 + threadIdx.x) * 8;
      float4 p = *(const float4*)(x + i);
      float4 q = *(const float4*)(x + i + 4);
      union { unsigned u[4]; bf16x8 v; } r;
      r.u[0] = pack2(p.x, p.y); r.u[1] = pack2(p.z, p.w);
      r.u[2] = pack2(q.x, q.y); r.u[3] = pack2(q.z, q.w);
      *(bf16x8*)(xb + i) = r.v;
    }
  }
  // phase 2: router dot + top-k (no barrier needed; phase 1 wrote only xb)
  const int t0 = tb + (threadIdx.x >> 6) * 4;
  const float4* wrow = (const float4*)(wr + (size_t)lane * H_DIM);
  const float4* xr0 = (const float4*)(x + (size_t)(t0 + 0) * H_DIM);
  const float4* xr1 = (const float4*)(x + (size_t)(t0 + 1) * H_DIM);
  const float4* xr2 = (const float4*)(x + (size_t)(t0 + 2) * H_DIM);
  const float4* xr3 = (const float4*)(x + (size_t)(t0 + 3) * H_DIM);
  float acc[4] = {0.f, 0.f, 0.f, 0.f};
  for (int i = 0; i < H_DIM / 4; ++i) {
    float4 b = wrow[i];
    float4 a0 = xr0[i], a1 = xr1[i], a2 = xr2[i], a3 = xr3[i];
    acc[0] = fmaf(a0.x,b.x,fmaf(a0.y,b.y,fmaf(a0.z,b.z,fmaf(a0.w,b.w,acc[0]))));
    acc[1] = fmaf(a1.x,b.x,fmaf(a1.y,b.y,fmaf(a1.z,b.z,fmaf(a1.w,b.w,acc[1]))));
    acc[2] = fmaf(a2.x,b.x,fmaf(a2.y,b.y,fmaf(a2.z,b.z,fmaf(a2.w,b.w,acc[2]))));
    acc[3] = fmaf(a3.x,b.x,fmaf(a3.y,b.y,fmaf(a3.z,b.z,fmaf(a3.w,b.w,acc[3]))));
  }
#pragma unroll
  for (int j = 0; j < 4; ++j) {
    float cur = acc[j];
    float val[TOPK]; int idx[TOPK];
#pragma unroll
    for (int r = 0; r < TOPK; ++r) {
      float bv = cur; int bi = lane;
#pragma unroll
      for (int off = 32; off > 0; off >>= 1) {   // argmax, ties -> lower index
        float ov = __shfl_xor(bv, off);
        int   oi = __shfl_xor(bi, off);
        if (ov > bv || (ov == bv && oi < bi)) { bv = ov; bi = oi; }
      }
      val[r] = bv; idx[r] = bi;
      if (lane == bi) cur = -INFINITY;
    }
    float m = val[0], s = 0.f, w[TOPK];
#pragma unroll
    for (int r = 0; r < TOPK; ++r) { w[r] = expf(val[r] - m); s += w[r]; }
    if (lane < TOPK) {
      topk_idx[(t0 + j) * TOPK + lane] = idx[lane];
      topk_w [(t0 + j) * TOPK + lane] = w[lane] / s;
    }
  }
}

// ---------------- K2: stable rank within expert (4 chunks in flight) -------
__global__ __launch_bounds__(1024) void k_rank(const int* __restrict__ topk_idx,
                                               int* __restrict__ pair_pos,
                                               int* __restrict__ slot_token,
                                               int* __restrict__ cnts) {
  __shared__ int s_run[64];
  __shared__ int s_whist[16][64];
  const int tid = threadIdx.x, lane = tid & 63, wv = tid >> 6;   // wv in [0,16)
  const int sub = wv >> 2;                 // chunk-in-flight 0..3
  if (tid < 64) s_run[tid] = 0;
  for (int it = 0; it < 16; ++it) {
    const int p = (it * 4 + sub) * 256 + (tid & 255);
    const int e = topk_idx[p];
    __syncthreads();
    s_whist[wv][lane] = 0;
    __syncthreads();
    unsigned long long m = ~0ull;
#pragma unroll
    for (int b = 0; b < 6; ++b) {
      unsigned long long bb = __ballot((e >> b) & 1);
      m &= ((e >> b) & 1) ? bb : ~bb;
    }
    const int rw = __popcll(m & ((1ull << lane) - 1ull));
    if (rw == 0) s_whist[wv][e] = __popcll(m);
    __syncthreads();
    int off = rw;
    for (int w2 = 0; w2 < wv; ++w2) off += s_whist[w2][e];
    const int pos = s_run[e] + off;
    pair_pos[p] = pos;
    if (pos < CAPE) slot_token[e * CAPE + pos] = p >> 3;
    __syncthreads();
    if (tid < 64) {
      int tsum = 0;
#pragma unroll
      for (int w2 = 0; w2 < 16; ++w2) tsum += s_whist[w2][tid];
      s_run[tid] += tsum;
    }
  }
  __syncthreads();
  if (tid < 64) cnts[tid] = s_run[tid];
}

// ---------------- K3: fused gate+up GEMM + SwiGLU -> act (bf16) ------------
// Round-17 champion VERBATIM.
__global__ __launch_bounds__(512) void k_gateup(const unsigned short* __restrict__ xb,
                                                const float* __restrict__ wg,
                                                const float* __restrict__ wu,
                                                const int* __restrict__ slot_token,
                                                const int* __restrict__ cnts,
                                                unsigned short* __restrict__ act) {
  const int NB = NEXP * MTMAX * 6;
  const int v = (blockIdx.x & 7) * (NB / 8) + (blockIdx.x >> 3);  // XCD chunk swizzle
  const int e = v / (MTMAX * 6);
  const int rem = v % (MTMAX * 6);
  const int mt = rem / 6, nt = rem % 6;

  int cnt = cnts[e]; cnt = cnt < CAPE ? cnt : CAPE;
  if (cnt <= 0 || mt * 128 >= cnt) return;
  const int m0 = mt << 7;

  __shared__ __align__(16) short As[2][128 * LDW];   // 20 KiB
  __shared__ __align__(16) short Bg[2][128 * LDW];   // 20 KiB
  __shared__ __align__(16) short Bu[2][128 * LDW];   // 20 KiB

  const int tid = threadIdx.x;
  const int lane = tid & 63, wave = tid >> 6;
  const int wm = wave >> 2, wn = wave & 3;       // 2x4 wave grid, 64x32 tiles
  const int lr = lane & 15, lg = lane >> 4;

  const int a_row = tid >> 2, a_ko = (tid & 3) * 8;
  const int b_mat = tid >> 8;            // 0: gate, 1: up (wave-uniform)
  const int b_idx = tid & 255;
  const int b_kq = b_idx & 7, b_nq = b_idx >> 3;
  const size_t wbase = (size_t)e * H_DIM * I_DIM + (size_t)nt * 128;

  const int tok = (m0 + a_row < cnt) ? slot_token[e * CAPE + m0 + a_row] : 0;
  const unsigned short* xr = xb + (size_t)tok * H_DIM + a_ko;
  const float* bp  = (b_mat ? wu : wg) + wbase + (size_t)(4 * b_kq) * I_DIM + 4 * b_nq;
  short* Bdst0 = b_mat ? Bu[0] : Bg[0];
  short* Bdst1 = b_mat ? Bu[1] : Bg[1];

  f32x4 accg[4][2], accu[4][2];
#pragma unroll
  for (int mi = 0; mi < 4; ++mi)
#pragma unroll
    for (int ni = 0; ni < 2; ++ni) {
      accg[mi][ni] = (f32x4){0.f, 0.f, 0.f, 0.f};
      accu[mi][ni] = (f32x4){0.f, 0.f, 0.f, 0.f};
    }

  struct Tile { bf16x8 a; float4 b[4]; };

  auto LOAD = [&](Tile& Tl, int kt) {
    const int k0 = kt * 32;
    Tl.a = *(const bf16x8*)(xr + k0);
    const float* r0 = bp + (size_t)k0 * I_DIM;
#pragma unroll
    for (int j = 0; j < 4; ++j)
      Tl.b[j] = *(const float4*)(r0 + (size_t)j * I_DIM);
  };
  auto STORE = [&](const Tile& Tl, int b) {
    *(bf16x8*)(&As[b][a_row * LDW + a_ko]) = Tl.a;
    short* Bd = b ? Bdst1 : Bdst0;
    const float* q0 = (const float*)&Tl.b[0];
    const float* q1 = (const float*)&Tl.b[1];
    const float* q2 = (const float*)&Tl.b[2];
    const float* q3 = (const float*)&Tl.b[3];
#pragma unroll
    for (int i = 0; i < 4; ++i) {
      uint2 w = { pack2(q0[i], q1[i]), pack2(q2[i], q3[i]) };  // k 4kq..4kq+3
      *(uint2*)(&Bd[(4 * b_nq + i) * LDW + 4 * b_kq]) = w;
    }
  };
  auto COMPUTE = [&](int b) {
    bf16x8 a[4], bg[2], bu[2];
#pragma unroll
    for (int mi = 0; mi < 4; ++mi)
      a[mi] = *(const bf16x8*)(&As[b][(wm * 64 + mi * 16 + lr) * LDW + lg * 8]);
#pragma unroll
    for (int ni = 0; ni < 2; ++ni) {
      bg[ni] = *(const bf16x8*)(&Bg[b][(wn * 32 + ni * 16 + lr) * LDW + lg * 8]);
      bu[ni] = *(const bf16x8*)(&Bu[b][(wn * 32 + ni * 16 + lr) * LDW + lg * 8]);
    }
#pragma unroll
    for (int mi = 0; mi < 4; ++mi)
#pragma unroll
      for (int ni = 0; ni < 2; ++ni) {
        accg[mi][ni] = __builtin_amdgcn_mfma_f32_16x16x32_bf16(a[mi], bg[ni], accg[mi][ni], 0, 0, 0);
        accu[mi][ni] = __builtin_amdgcn_mfma_f32_16x16x32_bf16(a[mi], bu[ni], accu[mi][ni], 0, 0, 0);
      }
  };

  const int NK = H_DIM / 32;   // 64, even
  Tile tA, tB;
  LOAD(tA, 0);
  STORE(tA, 0);                 // waits only tA's loads
  LOAD(tB, 1);
  __syncthreads();

  int t = 0;
#pragma unroll 1
  for (; t + 2 < NK; t += 2) {
    LOAD(tA, t + 2);            // issued early: a full COMPUTE before the drain
    COMPUTE(0);                 // tile t
    STORE(tB, 1);               // tile t+1
    __syncthreads();
    LOAD(tB, t + 3);
    COMPUTE(1);                 // tile t+1
    STORE(tA, 0);               // tile t+2
    __syncthreads();
  }
  COMPUTE(0);                   // tile NK-2
  STORE(tB, 1);                 // tile NK-1
  __syncthreads();
  COMPUTE(1);                   // tile NK-1

  // epilogue: silu(g)*u -> bf16 act (pad rows skipped; never read for output)
#pragma unroll
  for (int mi = 0; mi < 4; ++mi)
#pragma unroll
    for (int r = 0; r < 4; ++r) {
      const int row = m0 + wm * 64 + mi * 16 + lg * 4 + r;
      if (row >= cnt) continue;
#pragma unroll
      for (int ni = 0; ni < 2; ++ni) {
        const int col = nt * 128 + wn * 32 + ni * 16 + lr;
        const float g = accg[mi][ni][r], u = accu[mi][ni][r];
        const float vv = (g / (1.f + __expf(-g))) * u;
        act[(size_t)(e * CAPE + row) * I_DIM + col] = f2bf(vv);
      }
    }
}

// ---------------- K4: down GEMM -> y (bf16) --------------------------------
// Round-17 champion verbatim.
__global__ __launch_bounds__(512) void k_down(const unsigned short* __restrict__ act,
                                              const float* __restrict__ wd,
                                              const int* __restrict__ cnts,
                                              unsigned short* __restrict__ y) {
  const int NB = NEXP * MTMAX * 16;
  const int v = (blockIdx.x & 7) * (NB / 8) + (blockIdx.x >> 3);
  const int e = v / (MTMAX * 16);
  const int rem = v % (MTMAX * 16);
  const int mt = rem / 16, nt = rem % 16;

  int cnt = cnts[e]; cnt = cnt < CAPE ? cnt : CAPE;
  if (cnt <= 0 || mt * 128 >= cnt) return;
  const int m0 = mt << 7;

  __shared__ __align__(16) short As[2][128 * LDW];
  __shared__ __align__(16) short Bt[2][128 * LDW];

  const int tid = threadIdx.x;
  const int lane = tid & 63, wave = tid >> 6;
  const int wm = wave >> 2, wn = wave & 3;
  const int lr = lane & 15, lg = lane >> 4;

  const int role = tid >> 8;             // 0 (waves 0-3): B stager; 1: A stager
  const int ridx = tid & 255;
  const int b_kq = ridx & 7, b_nq = ridx >> 3;
  const int a_row = ridx >> 1, a_half = ridx & 1;
  const size_t wbase = (size_t)e * I_DIM * H_DIM + (size_t)nt * 128;

  const unsigned short* ap = act + (size_t)(e * CAPE + m0 + a_row) * I_DIM + a_half * 16;
  const float* bp = wd + wbase + (size_t)(4 * b_kq) * H_DIM + 4 * b_nq;

  f32x4 acc[4][2];
#pragma unroll
  for (int mi = 0; mi < 4; ++mi)
#pragma unroll
    for (int ni = 0; ni < 2; ++ni) acc[mi][ni] = (f32x4){0.f, 0.f, 0.f, 0.f};

  struct Tile { bf16x8 a0, a1; float4 b[4]; };

  auto LOAD = [&](Tile& Tl, int kt) {
    const int k0 = kt * 32;
    if (role) {
      Tl.a0 = *(const bf16x8*)(ap + k0);
      Tl.a1 = *(const bf16x8*)(ap + k0 + 8);
    } else {
      const float* r0 = bp + (size_t)k0 * H_DIM;
#pragma unroll
      for (int j = 0; j < 4; ++j)
        Tl.b[j] = *(const float4*)(r0 + (size_t)j * H_DIM);
    }
  };
  auto STORE = [&](const Tile& Tl, int b) {
    if (role) {
      *(bf16x8*)(&As[b][a_row * LDW + a_half * 16])     = Tl.a0;
      *(bf16x8*)(&As[b][a_row * LDW + a_half * 16 + 8]) = Tl.a1;
    } else {
      const float* q0 = (const float*)&Tl.b[0];
      const float* q1 = (const float*)&Tl.b[1];
      const float* q2 = (const float*)&Tl.b[2];
      const float* q3 = (const float*)&Tl.b[3];
#pragma unroll
      for (int i = 0; i < 4; ++i) {
        uint2 w = { pack2(q0[i], q1[i]), pack2(q2[i], q3[i]) };  // k 4kq..4kq+3
        *(uint2*)(&Bt[b][(4 * b_nq + i) * LDW + 4 * b_kq]) = w;
      }
    }
  };
  auto COMPUTE = [&](int b) {
    bf16x8 a[4], bb[2];
#pragma unroll
    for (int mi = 0; mi < 4; ++mi)
      a[mi] = *(const bf16x8*)(&As[b][(wm * 64 + mi * 16 + lr) * LDW + lg * 8]);
#pragma unroll
    for (int ni = 0; ni < 2; ++ni)
      bb[ni] = *(const bf16x8*)(&Bt[b][(wn * 32 + ni * 16 + lr) * LDW + lg * 8]);
#pragma unroll
    for (int mi = 0; mi < 4; ++mi)
#pragma unroll
      for (int ni = 0; ni < 2; ++ni)
        acc[mi][ni] = __builtin_amdgcn_mfma_f32_16x16x32_bf16(a[mi], bb[ni], acc[mi][ni], 0, 0, 0);
  };

  const int NK = I_DIM / 32;   // 24, even
  Tile tA, tB;
  LOAD(tA, 0);
  STORE(tA, 0);
  LOAD(tB, 1);
  __syncthreads();

  int t = 0;
#pragma unroll 1
  for (; t + 2 < NK; t += 2) {
    LOAD(tA, t + 2);
    COMPUTE(0);
    STORE(tB, 1);
    __syncthreads();
    LOAD(tB, t + 3);
    COMPUTE(1);
    STORE(tA, 0);
    __syncthreads();
  }
  COMPUTE(0);
  STORE(tB, 1);
  __syncthreads();
  COMPUTE(1);

#pragma unroll
  for (int mi = 0; mi < 4; ++mi)
#pragma unroll
    for (int r = 0; r < 4; ++r) {
      const int row = m0 + wm * 64 + mi * 16 + lg * 4 + r;
      if (row >= cnt) continue;
#pragma unroll
      for (int ni = 0; ni < 2; ++ni) {
        const int col = nt * 128 + wn * 32 + ni * 16 + lr;
        y[(size_t)(e * CAPE + row) * H_DIM + col] = f2bf(acc[mi][ni][r]);
      }
    }
}

// ---------------- K5: combine (4 tokens per block, deterministic gather) ---
__global__ __launch_bounds__(256) void k_combine(const unsigned short* __restrict__ y,
                                                 const int* __restrict__ topk_idx,
                                                 const float* __restrict__ topk_w,
                                                 const int* __restrict__ pair_pos,
                                                 float* __restrict__ out) {
  __shared__ int s_e[4][TOPK]; __shared__ int s_p[4][TOPK]; __shared__ float s_w[4][TOPK];
  const int tb = blockIdx.x * 4;
  if (threadIdx.x < 4 * TOPK) {
    const int j = threadIdx.x >> 3, k = threadIdx.x & 7;
    const int t = tb + j;
    s_e[j][k] = topk_idx[t * TOPK + k];
    s_p[j][k] = pair_pos[t * TOPK + k];
    s_w[j][k] = topk_w [t * TOPK + k];
  }
  __syncthreads();
  const int h0 = threadIdx.x * 8;
#pragma unroll
  for (int j = 0; j < 4; ++j) {
    const int t = tb + j;
    float acc[8] = {0.f, 0.f, 0.f, 0.f, 0.f, 0.f, 0.f, 0.f};
#pragma unroll
    for (int k = 0; k < TOPK; ++k) {
      const int pos = s_p[j][k];
      if (pos >= CAPE) continue;
      const float w = s_w[j][k];
      const bf16x8 vv = *(const bf16x8*)(&y[(size_t)(s_e[j][k] * CAPE + pos) * H_DIM + h0]);
#pragma unroll
      for (int jj = 0; jj < 8; ++jj) acc[jj] += w * bf2f((unsigned short)vv[jj]);
    }
    float4 o0 = {acc[0], acc[1], acc[2], acc[3]};
    float4 o1 = {acc[4], acc[5], acc[6], acc[7]};
    *(float4*)(out + (size_t)t * H_DIM + h0)     = o0;
    *(float4*)(out + (size_t)t * H_DIM + h0 + 4) = o1;
  }
}

// ---------------------------------------------------------------------------
extern "C" void kernel_launch(void* const* d_in, const int* in_sizes, int n_in,
                              void* d_out, int out_size, void* d_ws, size_t ws_size,
                              hipStream_t stream) {
  const float* x   = (const float*)d_in[0];
  const float* wr  = (const float*)d_in[1];
  const float* wgt = (const float*)d_in[2];
  const float* wup = (const float*)d_in[3];
  const float* wdn = (const float*)d_in[4];
  float* out = (float*)d_out;

  char* ws = (char*)d_ws;
  int*            topk_idx   = (int*)(ws);                    //  64 KiB
  float*          topk_w     = (float*)(ws + 65536);          //  64 KiB
  int*            pair_pos   = (int*)(ws + 131072);           //  64 KiB
  int*            cnts       = (int*)(ws + 196608);           // 256 B
  int*            slot_token = (int*)(ws + 196864);           // 128 KiB
  unsigned short* xb         = (unsigned short*)(ws + 327936);            //  8 MiB
  unsigned short* act        = (unsigned short*)(ws + 327936 + 8388608);  // 48 MiB
  unsigned short* yb         = (unsigned short*)(ws + 327936 + 8388608 + 50331648); // 128 MiB

  k_router <<<dim3(T_TOK / 16),       dim3(256), 0, stream>>>(x, wr, xb, topk_idx, topk_w);
  k_rank   <<<dim3(1),                dim3(1024), 0, stream>>>(topk_idx, pair_pos, slot_token, cnts);
  k_gateup <<<dim3(NEXP * MTMAX * 6), dim3(512), 0, stream>>>(xb, wgt, wup, slot_token, cnts, act);
  k_down   <<<dim3(NEXP * MTMAX * 16),dim3(512), 0, stream>>>(act, wdn, cnts, yb);
  k_combine<<<dim3(T_TOK / 4),        dim3(256), 0, stream>>>(yb, topk_idx, topk_w, pair_pos, out);
}

// Round 19
// 711.894 us; speedup vs baseline: 1.0085x; 1.0085x over previous
//
#include <hip/hip_runtime.h>
#include <hip/hip_bf16.h>
#include <math.h>

// Problem constants (Qwen3 MoE block)
#define T_TOK 2048
#define H_DIM 2048
#define NEXP  64
#define TOPK  8
#define I_DIM 768
#define CAPE  512
#define MTMAX 4   // CAPE/128
#define LDW   40  // LDS row stride in shorts (80B). MUST be multiple of 8 shorts
                  // (16B) or ds_read_b128/ds_write_b64 lose alignment.

typedef short bf16x8 __attribute__((ext_vector_type(8)));
typedef float f32x4  __attribute__((ext_vector_type(4)));

__device__ __forceinline__ unsigned short f2bf(float f) {
  unsigned u = __float_as_uint(f);
  u += 0x7fffu + ((u >> 16) & 1u);   // RNE
  return (unsigned short)(u >> 16);
}
__device__ __forceinline__ float bf2f(unsigned short b) {
  return __uint_as_float(((unsigned)b) << 16);
}
__device__ __forceinline__ unsigned pack2(float lo, float hi) {
  __hip_bfloat162 h = __float22bfloat162_rn(make_float2(lo, hi));  // v_cvt_pk_bf16_f32
  unsigned r; __builtin_memcpy(&r, &h, 4); return r;
}

// ---------------- K0: x -> bf16 (one-time; numerics identical) -------------
__global__ __launch_bounds__(256) void k_xcvt(const float* __restrict__ x,
                                              unsigned short* __restrict__ xb) {
  const size_t i = ((size_t)blockIdx.x * 256 + threadIdx.x) * 8;
  float4 p = *(const float4*)(x + i);
  float4 q = *(const float4*)(x + i + 4);
  union { unsigned u[4]; bf16x8 v; } r;
  r.u[0] = pack2(p.x, p.y); r.u[1] = pack2(p.z, p.w);
  r.u[2] = pack2(q.x, q.y); r.u[3] = pack2(q.z, q.w);
  *(bf16x8*)(xb + i) = r.v;
}

// ---------------- K1: router, 4 tokens per wave (w-scatter amortized 4x) ---
__global__ __launch_bounds__(256) void k_router(const float* __restrict__ x,
                                                const float* __restrict__ wr,
                                                int* __restrict__ topk_idx,
                                                float* __restrict__ topk_w) {
  const int lane = threadIdx.x & 63;
  const int t0 = blockIdx.x * 16 + (threadIdx.x >> 6) * 4;
  const float4* wrow = (const float4*)(wr + (size_t)lane * H_DIM);
  const float4* xr0 = (const float4*)(x + (size_t)(t0 + 0) * H_DIM);
  const float4* xr1 = (const float4*)(x + (size_t)(t0 + 1) * H_DIM);
  const float4* xr2 = (const float4*)(x + (size_t)(t0 + 2) * H_DIM);
  const float4* xr3 = (const float4*)(x + (size_t)(t0 + 3) * H_DIM);
  float acc[4] = {0.f, 0.f, 0.f, 0.f};
  for (int i = 0; i < H_DIM / 4; ++i) {
    float4 b = wrow[i];
    float4 a0 = xr0[i], a1 = xr1[i], a2 = xr2[i], a3 = xr3[i];
    acc[0] = fmaf(a0.x,b.x,fmaf(a0.y,b.y,fmaf(a0.z,b.z,fmaf(a0.w,b.w,acc[0]))));
    acc[1] = fmaf(a1.x,b.x,fmaf(a1.y,b.y,fmaf(a1.z,b.z,fmaf(a1.w,b.w,acc[1]))));
    acc[2] = fmaf(a2.x,b.x,fmaf(a2.y,b.y,fmaf(a2.z,b.z,fmaf(a2.w,b.w,acc[2]))));
    acc[3] = fmaf(a3.x,b.x,fmaf(a3.y,b.y,fmaf(a3.z,b.z,fmaf(a3.w,b.w,acc[3]))));
  }
#pragma unroll
  for (int j = 0; j < 4; ++j) {
    float cur = acc[j];
    float val[TOPK]; int idx[TOPK];
#pragma unroll
    for (int r = 0; r < TOPK; ++r) {
      float bv = cur; int bi = lane;
#pragma unroll
      for (int off = 32; off > 0; off >>= 1) {   // argmax, ties -> lower index
        float ov = __shfl_xor(bv, off);
        int   oi = __shfl_xor(bi, off);
        if (ov > bv || (ov == bv && oi < bi)) { bv = ov; bi = oi; }
      }
      val[r] = bv; idx[r] = bi;
      if (lane == bi) cur = -INFINITY;
    }
    float m = val[0], s = 0.f, w[TOPK];
#pragma unroll
    for (int r = 0; r < TOPK; ++r) { w[r] = expf(val[r] - m); s += w[r]; }
    if (lane < TOPK) {
      topk_idx[(t0 + j) * TOPK + lane] = idx[lane];
      topk_w [(t0 + j) * TOPK + lane] = w[lane] / s;
    }
  }
}

// ---------------- K2: stable rank within expert (4 chunks in flight) -------
__global__ __launch_bounds__(1024) void k_rank(const int* __restrict__ topk_idx,
                                               int* __restrict__ pair_pos,
                                               int* __restrict__ slot_token,
                                               int* __restrict__ cnts) {
  __shared__ int s_run[64];
  __shared__ int s_whist[16][64];
  const int tid = threadIdx.x, lane = tid & 63, wv = tid >> 6;   // wv in [0,16)
  const int sub = wv >> 2;                 // chunk-in-flight 0..3
  if (tid < 64) s_run[tid] = 0;
  for (int it = 0; it < 16; ++it) {
    const int p = (it * 4 + sub) * 256 + (tid & 255);
    const int e = topk_idx[p];
    __syncthreads();
    s_whist[wv][lane] = 0;
    __syncthreads();
    unsigned long long m = ~0ull;
#pragma unroll
    for (int b = 0; b < 6; ++b) {
      unsigned long long bb = __ballot((e >> b) & 1);
      m &= ((e >> b) & 1) ? bb : ~bb;
    }
    const int rw = __popcll(m & ((1ull << lane) - 1ull));
    if (rw == 0) s_whist[wv][e] = __popcll(m);
    __syncthreads();
    int off = rw;
    for (int w2 = 0; w2 < wv; ++w2) off += s_whist[w2][e];
    const int pos = s_run[e] + off;
    pair_pos[p] = pos;
    if (pos < CAPE) slot_token[e * CAPE + pos] = p >> 3;
    __syncthreads();
    if (tid < 64) {
      int tsum = 0;
#pragma unroll
      for (int w2 = 0; w2 < 16; ++w2) tsum += s_whist[w2][tid];
      s_run[tid] += tsum;
    }
  }
  __syncthreads();
  if (tid < 64) cnts[tid] = s_run[tid];
}

// ---------------- K3: fused gate+up GEMM + SwiGLU -> act (bf16) ------------
// Session champion: bf16 A from xb (1 load + 1 b128 write), k-quad b64 B
// transpose staging, LDW=40, 2-deep reg rotation, pad-row write elision.
__global__ __launch_bounds__(512) void k_gateup(const unsigned short* __restrict__ xb,
                                                const float* __restrict__ wg,
                                                const float* __restrict__ wu,
                                                const int* __restrict__ slot_token,
                                                const int* __restrict__ cnts,
                                                unsigned short* __restrict__ act) {
  const int NB = NEXP * MTMAX * 6;
  const int v = (blockIdx.x & 7) * (NB / 8) + (blockIdx.x >> 3);  // XCD chunk swizzle
  const int e = v / (MTMAX * 6);
  const int rem = v % (MTMAX * 6);
  const int mt = rem / 6, nt = rem % 6;

  int cnt = cnts[e]; cnt = cnt < CAPE ? cnt : CAPE;
  if (cnt <= 0 || mt * 128 >= cnt) return;
  const int m0 = mt << 7;

  __shared__ __align__(16) short As[2][128 * LDW];   // 20 KiB
  __shared__ __align__(16) short Bg[2][128 * LDW];   // 20 KiB
  __shared__ __align__(16) short Bu[2][128 * LDW];   // 20 KiB

  const int tid = threadIdx.x;
  const int lane = tid & 63, wave = tid >> 6;
  const int wm = wave >> 2, wn = wave & 3;       // 2x4 wave grid, 64x32 tiles
  const int lr = lane & 15, lg = lane >> 4;

  const int a_row = tid >> 2, a_ko = (tid & 3) * 8;
  const int b_mat = tid >> 8;            // 0: gate, 1: up (wave-uniform)
  const int b_idx = tid & 255;
  const int b_kq = b_idx & 7, b_nq = b_idx >> 3;
  const size_t wbase = (size_t)e * H_DIM * I_DIM + (size_t)nt * 128;

  const int tok = (m0 + a_row < cnt) ? slot_token[e * CAPE + m0 + a_row] : 0;
  const unsigned short* xr = xb + (size_t)tok * H_DIM + a_ko;
  const float* bp  = (b_mat ? wu : wg) + wbase + (size_t)(4 * b_kq) * I_DIM + 4 * b_nq;
  short* Bdst0 = b_mat ? Bu[0] : Bg[0];
  short* Bdst1 = b_mat ? Bu[1] : Bg[1];

  f32x4 accg[4][2], accu[4][2];
#pragma unroll
  for (int mi = 0; mi < 4; ++mi)
#pragma unroll
    for (int ni = 0; ni < 2; ++ni) {
      accg[mi][ni] = (f32x4){0.f, 0.f, 0.f, 0.f};
      accu[mi][ni] = (f32x4){0.f, 0.f, 0.f, 0.f};
    }

  struct Tile { bf16x8 a; float4 b[4]; };

  auto LOAD = [&](Tile& Tl, int kt) {
    const int k0 = kt * 32;
    Tl.a = *(const bf16x8*)(xr + k0);
    const float* r0 = bp + (size_t)k0 * I_DIM;
#pragma unroll
    for (int j = 0; j < 4; ++j)
      Tl.b[j] = *(const float4*)(r0 + (size_t)j * I_DIM);
  };
  auto STORE = [&](const Tile& Tl, int b) {
    *(bf16x8*)(&As[b][a_row * LDW + a_ko]) = Tl.a;
    short* Bd = b ? Bdst1 : Bdst0;
    const float* q0 = (const float*)&Tl.b[0];
    const float* q1 = (const float*)&Tl.b[1];
    const float* q2 = (const float*)&Tl.b[2];
    const float* q3 = (const float*)&Tl.b[3];
#pragma unroll
    for (int i = 0; i < 4; ++i) {
      uint2 w = { pack2(q0[i], q1[i]), pack2(q2[i], q3[i]) };  // k 4kq..4kq+3
      *(uint2*)(&Bd[(4 * b_nq + i) * LDW + 4 * b_kq]) = w;
    }
  };
  auto COMPUTE = [&](int b) {
    bf16x8 a[4], bg[2], bu[2];
#pragma unroll
    for (int mi = 0; mi < 4; ++mi)
      a[mi] = *(const bf16x8*)(&As[b][(wm * 64 + mi * 16 + lr) * LDW + lg * 8]);
#pragma unroll
    for (int ni = 0; ni < 2; ++ni) {
      bg[ni] = *(const bf16x8*)(&Bg[b][(wn * 32 + ni * 16 + lr) * LDW + lg * 8]);
      bu[ni] = *(const bf16x8*)(&Bu[b][(wn * 32 + ni * 16 + lr) * LDW + lg * 8]);
    }
#pragma unroll
    for (int mi = 0; mi < 4; ++mi)
#pragma unroll
      for (int ni = 0; ni < 2; ++ni) {
        accg[mi][ni] = __builtin_amdgcn_mfma_f32_16x16x32_bf16(a[mi], bg[ni], accg[mi][ni], 0, 0, 0);
        accu[mi][ni] = __builtin_amdgcn_mfma_f32_16x16x32_bf16(a[mi], bu[ni], accu[mi][ni], 0, 0, 0);
      }
  };

  const int NK = H_DIM / 32;   // 64, even
  Tile tA, tB;
  LOAD(tA, 0);
  STORE(tA, 0);                 // waits only tA's loads
  LOAD(tB, 1);
  __syncthreads();

  int t = 0;
#pragma unroll 1
  for (; t + 2 < NK; t += 2) {
    LOAD(tA, t + 2);            // issued early: a full COMPUTE before the drain
    COMPUTE(0);                 // tile t
    STORE(tB, 1);               // tile t+1
    __syncthreads();
    LOAD(tB, t + 3);
    COMPUTE(1);                 // tile t+1
    STORE(tA, 0);               // tile t+2
    __syncthreads();
  }
  COMPUTE(0);                   // tile NK-2
  STORE(tB, 1);                 // tile NK-1
  __syncthreads();
  COMPUTE(1);                   // tile NK-1

  // epilogue: silu(g)*u -> bf16 act (pad rows skipped; never read for output)
#pragma unroll
  for (int mi = 0; mi < 4; ++mi)
#pragma unroll
    for (int r = 0; r < 4; ++r) {
      const int row = m0 + wm * 64 + mi * 16 + lg * 4 + r;
      if (row >= cnt) continue;
#pragma unroll
      for (int ni = 0; ni < 2; ++ni) {
        const int col = nt * 128 + wn * 32 + ni * 16 + lr;
        const float g = accg[mi][ni][r], u = accu[mi][ni][r];
        const float vv = (g / (1.f + __expf(-g))) * u;
        act[(size_t)(e * CAPE + row) * I_DIM + col] = f2bf(vv);
      }
    }
}

// ---------------- K4: down GEMM -> y (bf16) --------------------------------
// Champion: role-split staging (waves 0-3 B, waves 4-7 A), natural register
// allocation, pad-row write elision.
__global__ __launch_bounds__(512) void k_down(const unsigned short* __restrict__ act,
                                              const float* __restrict__ wd,
                                              const int* __restrict__ cnts,
                                              unsigned short* __restrict__ y) {
  const int NB = NEXP * MTMAX * 16;
  const int v = (blockIdx.x & 7) * (NB / 8) + (blockIdx.x >> 3);
  const int e = v / (MTMAX * 16);
  const int rem = v % (MTMAX * 16);
  const int mt = rem / 16, nt = rem % 16;

  int cnt = cnts[e]; cnt = cnt < CAPE ? cnt : CAPE;
  if (cnt <= 0 || mt * 128 >= cnt) return;
  const int m0 = mt << 7;

  __shared__ __align__(16) short As[2][128 * LDW];
  __shared__ __align__(16) short Bt[2][128 * LDW];

  const int tid = threadIdx.x;
  const int lane = tid & 63, wave = tid >> 6;
  const int wm = wave >> 2, wn = wave & 3;
  const int lr = lane & 15, lg = lane >> 4;

  const int role = tid >> 8;             // 0 (waves 0-3): B stager; 1: A stager
  const int ridx = tid & 255;
  const int b_kq = ridx & 7, b_nq = ridx >> 3;
  const int a_row = ridx >> 1, a_half = ridx & 1;
  const size_t wbase = (size_t)e * I_DIM * H_DIM + (size_t)nt * 128;

  const unsigned short* ap = act + (size_t)(e * CAPE + m0 + a_row) * I_DIM + a_half * 16;
  const float* bp = wd + wbase + (size_t)(4 * b_kq) * H_DIM + 4 * b_nq;

  f32x4 acc[4][2];
#pragma unroll
  for (int mi = 0; mi < 4; ++mi)
#pragma unroll
    for (int ni = 0; ni < 2; ++ni) acc[mi][ni] = (f32x4){0.f, 0.f, 0.f, 0.f};

  struct Tile { bf16x8 a0, a1; float4 b[4]; };

  auto LOAD = [&](Tile& Tl, int kt) {
    const int k0 = kt * 32;
    if (role) {
      Tl.a0 = *(const bf16x8*)(ap + k0);
      Tl.a1 = *(const bf16x8*)(ap + k0 + 8);
    } else {
      const float* r0 = bp + (size_t)k0 * H_DIM;
#pragma unroll
      for (int j = 0; j < 4; ++j)
        Tl.b[j] = *(const float4*)(r0 + (size_t)j * H_DIM);
    }
  };
  auto STORE = [&](const Tile& Tl, int b) {
    if (role) {
      *(bf16x8*)(&As[b][a_row * LDW + a_half * 16])     = Tl.a0;
      *(bf16x8*)(&As[b][a_row * LDW + a_half * 16 + 8]) = Tl.a1;
    } else {
      const float* q0 = (const float*)&Tl.b[0];
      const float* q1 = (const float*)&Tl.b[1];
      const float* q2 = (const float*)&Tl.b[2];
      const float* q3 = (const float*)&Tl.b[3];
#pragma unroll
      for (int i = 0; i < 4; ++i) {
        uint2 w = { pack2(q0[i], q1[i]), pack2(q2[i], q3[i]) };  // k 4kq..4kq+3
        *(uint2*)(&Bt[b][(4 * b_nq + i) * LDW + 4 * b_kq]) = w;
      }
    }
  };
  auto COMPUTE = [&](int b) {
    bf16x8 a[4], bb[2];
#pragma unroll
    for (int mi = 0; mi < 4; ++mi)
      a[mi] = *(const bf16x8*)(&As[b][(wm * 64 + mi * 16 + lr) * LDW + lg * 8]);
#pragma unroll
    for (int ni = 0; ni < 2; ++ni)
      bb[ni] = *(const bf16x8*)(&Bt[b][(wn * 32 + ni * 16 + lr) * LDW + lg * 8]);
#pragma unroll
    for (int mi = 0; mi < 4; ++mi)
#pragma unroll
      for (int ni = 0; ni < 2; ++ni)
        acc[mi][ni] = __builtin_amdgcn_mfma_f32_16x16x32_bf16(a[mi], bb[ni], acc[mi][ni], 0, 0, 0);
  };

  const int NK = I_DIM / 32;   // 24, even
  Tile tA, tB;
  LOAD(tA, 0);
  STORE(tA, 0);
  LOAD(tB, 1);
  __syncthreads();

  int t = 0;
#pragma unroll 1
  for (; t + 2 < NK; t += 2) {
    LOAD(tA, t + 2);
    COMPUTE(0);
    STORE(tB, 1);
    __syncthreads();
    LOAD(tB, t + 3);
    COMPUTE(1);
    STORE(tA, 0);
    __syncthreads();
  }
  COMPUTE(0);
  STORE(tB, 1);
  __syncthreads();
  COMPUTE(1);

#pragma unroll
  for (int mi = 0; mi < 4; ++mi)
#pragma unroll
    for (int r = 0; r < 4; ++r) {
      const int row = m0 + wm * 64 + mi * 16 + lg * 4 + r;
      if (row >= cnt) continue;
#pragma unroll
      for (int ni = 0; ni < 2; ++ni) {
        const int col = nt * 128 + wn * 32 + ni * 16 + lr;
        y[(size_t)(e * CAPE + row) * H_DIM + col] = f2bf(acc[mi][ni][r]);
      }
    }
}

// ---------------- K5: combine (deterministic gather) -----------------------
__global__ __launch_bounds__(256) void k_combine(const unsigned short* __restrict__ y,
                                                 const int* __restrict__ topk_idx,
                                                 const float* __restrict__ topk_w,
                                                 const int* __restrict__ pair_pos,
                                                 float* __restrict__ out) {
  const int t = blockIdx.x;
  __shared__ int s_e[TOPK]; __shared__ int s_p[TOPK]; __shared__ float s_w[TOPK];
  if (threadIdx.x < TOPK) {
    s_e[threadIdx.x] = topk_idx[t * TOPK + threadIdx.x];
    s_p[threadIdx.x] = pair_pos[t * TOPK + threadIdx.x];
    s_w[threadIdx.x] = topk_w [t * TOPK + threadIdx.x];
  }
  __syncthreads();
  const int h0 = threadIdx.x * 8;
  float acc[8] = {0.f, 0.f, 0.f, 0.f, 0.f, 0.f, 0.f, 0.f};
#pragma unroll
  for (int k = 0; k < TOPK; ++k) {
    const int pos = s_p[k];
    if (pos >= CAPE) continue;
    const float w = s_w[k];
    const bf16x8 vv = *(const bf16x8*)(&y[(size_t)(s_e[k] * CAPE + pos) * H_DIM + h0]);
#pragma unroll
    for (int j = 0; j < 8; ++j) acc[j] += w * bf2f((unsigned short)vv[j]);
  }
  float4 o0 = {acc[0], acc[1], acc[2], acc[3]};
  float4 o1 = {acc[4], acc[5], acc[6], acc[7]};
  *(float4*)(out + (size_t)t * H_DIM + h0)     = o0;
  *(float4*)(out + (size_t)t * H_DIM + h0 + 4) = o1;
}

// ---------------------------------------------------------------------------
extern "C" void kernel_launch(void* const* d_in, const int* in_sizes, int n_in,
                              void* d_out, int out_size, void* d_ws, size_t ws_size,
                              hipStream_t stream) {
  const float* x   = (const float*)d_in[0];
  const float* wr  = (const float*)d_in[1];
  const float* wgt = (const float*)d_in[2];
  const float* wup = (const float*)d_in[3];
  const float* wdn = (const float*)d_in[4];
  float* out = (float*)d_out;

  char* ws = (char*)d_ws;
  int*            topk_idx   = (int*)(ws);                    //  64 KiB
  float*          topk_w     = (float*)(ws + 65536);          //  64 KiB
  int*            pair_pos   = (int*)(ws + 131072);           //  64 KiB
  int*            cnts       = (int*)(ws + 196608);           // 256 B
  int*            slot_token = (int*)(ws + 196864);           // 128 KiB
  unsigned short* xb         = (unsigned short*)(ws + 327936);            //  8 MiB
  unsigned short* act        = (unsigned short*)(ws + 327936 + 8388608);  // 48 MiB
  unsigned short* yb         = (unsigned short*)(ws + 327936 + 8388608 + 50331648); // 128 MiB

  k_xcvt   <<<dim3(T_TOK * H_DIM / 2048), dim3(256), 0, stream>>>(x, xb);
  k_router <<<dim3(T_TOK / 16),       dim3(256), 0, stream>>>(x, wr, topk_idx, topk_w);
  k_rank   <<<dim3(1),                dim3(1024), 0, stream>>>(topk_idx, pair_pos, slot_token, cnts);
  k_gateup <<<dim3(NEXP * MTMAX * 6), dim3(512), 0, stream>>>(xb, wgt, wup, slot_token, cnts, act);
  k_down   <<<dim3(NEXP * MTMAX * 16),dim3(512), 0, stream>>>(act, wdn, cnts, yb);
  k_combine<<<dim3(T_TOK),            dim3(256), 0, stream>>>(yb, topk_idx, topk_w, pair_pos, out);
}